// Round 8
// baseline (373.160 us; speedup 1.0000x reference)
//
#include <hip/hip_runtime.h>
#include <hip/hip_cooperative_groups.h>

namespace cg = cooperative_groups;

#define NN 1000
#define HEADS_ 4
#define DM 128
#define EE 64000
#define NTOT 4000
#define ETOT 68000
#define CAP 48      // bucket holds ALL edges per dst: deg ~ Poisson(16)+1, P(>=48) ~ 1e-11
#define GRID 256    // 1 block/CU worst-case -> passes coop co-residency check

union SMem {
  struct { float As[128 * 64]; float Bs[64 * 64]; } g;                 // 48 KB
  struct { float q[2][4][DM], k[2][4][DM], v[2][4][DM];
           float aw[2][4][HEADS_][4]; } a;                             // 12.5 KB
  struct { int s[2][CAP]; float ex[2][CAP][HEADS_]; } gat;             // ~2 KB
};

// ---------------------------------------------------------------------------
// Tiled GEMM tile: C[m0..+128][n0..+64] = A @ Wt^T (+b1+b2), K in {64,128}.
// LDS m-major, k-group XOR swizzle; staging = direct b128 copies.
// SCORE: fused GAT score epilogue (h-GEMM; only rows<1000 are nonzero h_flat).
// REMAP: write row m=node*4+v to (b*4+v)*1000+n order (final output layout).
// ---------------------------------------------------------------------------
template <int K, int SCORE, int REMAP>
__device__ void gemm_tile(SMem* sm, int m0, int n0,
                          const float* __restrict__ A, const float* __restrict__ Wt,
                          const float* __restrict__ b1, const float* __restrict__ b2,
                          float* __restrict__ C, int N,
                          const float* __restrict__ att,
                          float* __restrict__ ssrc, float* __restrict__ sdst,
                          int tid, int by) {
  float* As = sm->g.As;
  float* Bs = sm->g.Bs;
  int tx = tid & 15, ty = tid >> 4;
  const float4* A4 = (const float4*)A;
  const float4* W4 = (const float4*)Wt;
  float acc[8][4] = {};

  for (int c = 0; c < K / 64; ++c) {
    __syncthreads();
    {
      int q = tid & 15;   // k-group slot within chunk
      int r0 = tid >> 4;  // 16 rows per pass
#pragma unroll
      for (int p = 0; p < 8; ++p) {  // A: 128 rows
        int r = r0 + p * 16;
        float4 v = A4[(size_t)(m0 + r) * (K / 4) + c * 16 + q];
        *(float4*)&As[r * 64 + ((q ^ (r & 15)) << 2)] = v;
      }
#pragma unroll
      for (int p = 0; p < 4; ++p) {  // B: 64 rows
        int r = r0 + p * 16;
        float4 v = W4[(size_t)(n0 + r) * (K / 4) + c * 16 + q];
        *(float4*)&Bs[r * 64 + ((q ^ (r & 15)) << 2)] = v;
      }
    }
    __syncthreads();
#pragma unroll 4
    for (int q = 0; q < 16; ++q) {
      float4 a[8], b[4];
#pragma unroll
      for (int i = 0; i < 8; ++i) {
        int r = ty * 8 + i;
        a[i] = *(const float4*)&As[r * 64 + ((q ^ (r & 15)) << 2)];
      }
#pragma unroll
      for (int j = 0; j < 4; ++j) {
        int rn = tx * 4 + j;
        b[j] = *(const float4*)&Bs[rn * 64 + ((q ^ (rn & 15)) << 2)];
      }
#pragma unroll
      for (int i = 0; i < 8; ++i)
#pragma unroll
        for (int j = 0; j < 4; ++j)
          acc[i][j] += a[i].x * b[j].x + a[i].y * b[j].y
                     + a[i].z * b[j].z + a[i].w * b[j].w;
    }
  }

  float bd[4] = {0.f, 0.f, 0.f, 0.f};
  int nc = n0 + tx * 4;
  if (b1) { bd[0] = b1[nc]; bd[1] = b1[nc+1]; bd[2] = b1[nc+2]; bd[3] = b1[nc+3]; }
  if (b2) { bd[0] += b2[nc]; bd[1] += b2[nc+1]; bd[2] += b2[nc+2]; bd[3] += b2[nc+3]; }
#pragma unroll
  for (int i = 0; i < 8; ++i) {
    int m = m0 + ty * 8 + i;
    int om = m;
    if (REMAP) {
      int node = m >> 2, v = m & 3;
      int b = node / NN, n = node - b * NN;
      om = (b * 4 + v) * NN + n;
    }
    float4 o = make_float4(acc[i][0] + bd[0], acc[i][1] + bd[1],
                           acc[i][2] + bd[2], acc[i][3] + bd[3]);
    *(float4*)&C[(size_t)om * N + nc] = o;
  }

  if (SCORE && m0 < NN) {  // uniform per block
    int hsel = tx >> 3;
    int h = by * 2 + hsel;
    int kb = (tx & 7) * 4;
    float a0[4], a1[4];
#pragma unroll
    for (int j = 0; j < 4; ++j) {
      a0[j] = att[h * 64 + kb + j];
      a1[j] = att[h * 64 + 32 + kb + j];
    }
#pragma unroll
    for (int i = 0; i < 8; ++i) {
      int m = m0 + ty * 8 + i;
      float p0 = 0.f, p1 = 0.f;
#pragma unroll
      for (int j = 0; j < 4; ++j) {
        float g = acc[i][j];
        float lr = g > 0.f ? g : 0.2f * g;
        p0 += a0[j] * lr;
        p1 += a1[j] * lr;
      }
      p0 += __shfl_xor(p0, 1, 16); p1 += __shfl_xor(p1, 1, 16);
      p0 += __shfl_xor(p0, 2, 16); p1 += __shfl_xor(p1, 2, 16);
      p0 += __shfl_xor(p0, 4, 16); p1 += __shfl_xor(p1, 4, 16);
      if ((tx & 7) == 0 && m < NN) {
        ssrc[m * HEADS_ + h] = p0;
        sdst[m * HEADS_ + h] = p1;
      }
    }
  }
}

// ---------------------------------------------------------------------------
// One cooperative kernel: the whole pipeline, grid.sync between phases.
// ---------------------------------------------------------------------------
__global__ __launch_bounds__(256, 2) void fused_kernel(
    const float* __restrict__ x, const float* __restrict__ W,
    const float* __restrict__ att,
    const float* __restrict__ inw, const float* __restrict__ inb,
    const float* __restrict__ outw, const float* __restrict__ outb,
    const float* __restrict__ bias, const int* __restrict__ ei,
    float* __restrict__ out,
    float* __restrict__ hbuf, float* __restrict__ hgat,
    float* __restrict__ qkv, float* __restrict__ ao,
    float* __restrict__ ssrc, float* __restrict__ sdst,
    int* __restrict__ cnt, int* __restrict__ elist) {
  cg::grid_group grid = cg::this_grid();
  __shared__ SMem sm;
  int bid = blockIdx.x;
  int tid = threadIdx.x;

  // ---------------- P0: h = x@W^T + score epilogue | zero cnt + score tails
  if (bid < 250) {
    int by = bid & 1;
    gemm_tile<64, 1, 0>(&sm, (bid >> 1) * 128, by * 64, x, W, nullptr, nullptr,
                        hbuf, 128, att, ssrc, sdst, tid, by);
  } else {
    // 28000 zero-items over 6 blocks x 256 threads, grid-strided
    for (int idx = (bid - 250) * 256 + tid; idx < 28000; idx += 6 * 256) {
      if (idx < NTOT) cnt[idx] = 0;
      int z = idx - NTOT;
      if (z >= 0 && z < 12000) ssrc[4000 + z] = 0.f;   // score rows 1000..3999
      int z2 = z - 12000;
      if (z2 >= 0) sdst[4000 + z2] = 0.f;
    }
  }
  grid.sync();

  // ---------------- P1: bucket build (ALL edges per dst, incl. self loops)
  for (int e = bid * 256 + tid; e < ETOT; e += GRID * 256) {
    int s, d;
    if (e < EE) { s = ei[e]; d = ei[EE + e]; }
    else { s = d = e - EE; }
    int pos = atomicAdd(&cnt[d], 1);
    if (pos < CAP) elist[d * CAP + pos] = s;
  }
  grid.sync();

  // ---------------- P2: gather: per-dst softmax (local denom) + aggregate
  for (int p = bid; p < NTOT / 2; p += GRID) {
    int li = tid >> 7, t = tid & 127;
    int d = p * 2 + li;
    int b = d / NN;
    int v = t >> 5, q = t & 31, h = q >> 3;
    int m = cnt[d]; if (m > CAP) m = CAP;
    // (a) stage src ids + exp(score) per head into LDS
    for (int base = 0; base < m; base += 32) {
      int i = base + (t >> 2);
      if (i < m) {
        int s = elist[d * CAP + i];
        if ((t & 3) == 0) sm.gat.s[li][i] = s;
        float sc = ssrc[s * HEADS_ + (t & 3)] + sdst[d * HEADS_ + (t & 3)];
        sm.gat.ex[li][i][t & 3] = __expf(sc);  // shift-invariant, scores O(1)
      }
    }
    __syncthreads();
    // (b) denom over ALL edges; numerator over active (same-block) edges
    float den = 1e-16f;
    float4 acc = make_float4(0.f, 0.f, 0.f, 0.f);
    const float* hbase = hbuf + ((size_t)(b * 4 + v) * NN) * DM + q * 4;
    for (int i = 0; i < m; ++i) {
      float ex = sm.gat.ex[li][i][h];
      den += ex;
      unsigned sl = (unsigned)(sm.gat.s[li][i] - b * NN);
      if (sl < NN) {  // block-diagonal h_full: only same-block srcs contribute
        float4 hv = *(const float4*)(hbase + (size_t)sl * DM);
        acc.x += ex * hv.x; acc.y += ex * hv.y;
        acc.z += ex * hv.z; acc.w += ex * hv.w;
      }
    }
    float r = 1.f / den;
    acc.x *= r; acc.y *= r; acc.z *= r; acc.w *= r;
    *(float4*)&hgat[((size_t)(d * 4 + v)) * DM + q * 4] = acc;
    __syncthreads();
  }
  grid.sync();

  // ---------------- P3: qkv = hgat @ inw^T + inb (node-major, 750 tiles)
  for (int tId = bid; tId < 750; tId += GRID)
    gemm_tile<128, 0, 0>(&sm, (tId / 6) * 128, (tId % 6) * 64, hgat, inw, inb,
                         nullptr, qkv, 384, nullptr, nullptr, nullptr, tid, 0);
  grid.sync();

  // ---------------- P4: attention over V, 2 nodes per block iteration
  for (int p = bid; p < NTOT / 2; p += GRID) {
    int li = tid >> 7, t = tid & 127;
    int node = p * 2 + li;
#pragma unroll
    for (int v = 0; v < 4; ++v) {
      size_t base = (size_t)(node * 4 + v) * 384;
      sm.a.q[li][v][t] = qkv[base + t];
      sm.a.k[li][v][t] = qkv[base + 128 + t];
      sm.a.v[li][v][t] = qkv[base + 256 + t];
    }
    __syncthreads();
    if (t < 64) {
      int vq = t >> 4, vk = (t >> 2) & 3, h = t & 3;
      float acc = 0.f;
#pragma unroll
      for (int kd = 0; kd < 32; ++kd)
        acc += sm.a.q[li][vq][h * 32 + kd] * sm.a.k[li][vk][h * 32 + kd];
      sm.a.aw[li][vq][h][vk] = acc * 0.17677669529663687f;  // 1/sqrt(32)
    }
    __syncthreads();
    if (t < 16) {
      int vq = t >> 2, h = t & 3;
      float mx = sm.a.aw[li][vq][h][0];
      for (int i = 1; i < 4; ++i) mx = fmaxf(mx, sm.a.aw[li][vq][h][i]);
      float e[4], s = 0.f;
      for (int i = 0; i < 4; ++i) { e[i] = __expf(sm.a.aw[li][vq][h][i] - mx); s += e[i]; }
      for (int i = 0; i < 4; ++i) sm.a.aw[li][vq][h][i] = e[i] / s;
    }
    __syncthreads();
    int h = t >> 5;
#pragma unroll
    for (int vq = 0; vq < 4; ++vq) {
      float acc = 0.f;
#pragma unroll
      for (int vk = 0; vk < 4; ++vk) acc += sm.a.aw[li][vq][h][vk] * sm.a.v[li][vk][t];
      ao[(size_t)(node * 4 + vq) * DM + t] = acc;
    }
    __syncthreads();
  }
  grid.sync();

  // ---------------- P5: out = ao @ outw^T + outb + bias, remap to (b,v,n)
  if (bid < 250) {
    gemm_tile<128, 0, 1>(&sm, (bid >> 1) * 128, (bid & 1) * 64, ao, outw, outb,
                         bias, out, 128, nullptr, nullptr, nullptr, tid, 0);
  }
}

extern "C" void kernel_launch(void* const* d_in, const int* in_sizes, int n_in,
                              void* d_out, int out_size, void* d_ws, size_t ws_size,
                              hipStream_t stream) {
  const float* x    = (const float*)d_in[0];
  const float* W    = (const float*)d_in[1];
  const float* att  = (const float*)d_in[2];
  const float* inw  = (const float*)d_in[3];
  const float* inb  = (const float*)d_in[4];
  const float* outw = (const float*)d_in[5];
  const float* outb = (const float*)d_in[6];
  const float* bias = (const float*)d_in[7];
  const int*   ei   = (const int*)d_in[8];
  float* out = (float*)d_out;

  float* ws = (float*)d_ws;
  float* hbuf  = ws;                       // 2,048,000
  float* hgat  = ws + 2100000;             // 2,048,000 (node-major)
  float* qkv   = ws + 4200000;             // 6,144,000 (node-major)
  float* ao    = ws + 10400000;            // 2,048,000 (node-major)
  float* ssrc  = ws + 12500000;            // 16,000
  float* sdst  = ssrc + 16000;             // 16,000
  int*   cnt   = (int*)(sdst + 16000);     //  4,000
  int*   elist = cnt + 4000;               // 192,000 (4000 x CAP)

  void* args[] = {(void*)&x, (void*)&W, (void*)&att, (void*)&inw, (void*)&inb,
                  (void*)&outw, (void*)&outb, (void*)&bias, (void*)&ei,
                  (void*)&out, (void*)&hbuf, (void*)&hgat, (void*)&qkv,
                  (void*)&ao, (void*)&ssrc, (void*)&sdst, (void*)&cnt,
                  (void*)&elist};
  (void)hipLaunchCooperativeKernel((const void*)fused_kernel, dim3(GRID),
                                   dim3(256), args, 0, stream);
}

// Round 10
// 150.361 us; speedup vs baseline: 2.4818x; 2.4818x over previous
//
#include <hip/hip_runtime.h>

#define NN 1000
#define HEADS_ 4
#define DM 128
#define EE 64000
#define NTOT 4000
#define ETOT 68000
#define CAP 48     // bucket holds ALL edges per dst: deg ~ Poisson(16)+1, P(>=48) ~ 1e-11
#define EB 34      // edge-builder blocks appended to the h-GEMM dispatch

// ---------------------------------------------------------------------------
// Tiled GEMM tile: C[m0..+128][n0..+64] = A @ Wt^T (+b1+b2), K in {64,128}.
// LDS m-major with k-group swizzle g = q ^ ((r>>2)&15):
//  - staging: 16 threads (q=0..15) per row -> writes cover all 16 groups, free
//  - a-frag reads (rows ty*8+i): 4 addresses/wave, 4 distinct bank-groups, free
//  - b-frag reads (rows tx*4+j): 16 addresses/wave, 16 distinct groups, 2-way
//    (free per m136).  [R3-R8 used g=q^(r&15): b-reads were 8-way = 2.94x]
// SCORE: fused GAT score epilogue (h-GEMM; only rows<1000 are nonzero h_flat).
// REMAP: write row m=node*4+v to (b*4+v)*1000+n order (final output layout).
// ---------------------------------------------------------------------------
template <int K, int SCORE, int REMAP>
__device__ void gemm_tile(int mi, int ni,
                          const float* __restrict__ A, const float* __restrict__ Wt,
                          const float* __restrict__ b1, const float* __restrict__ b2,
                          float* __restrict__ C, int N,
                          const float* __restrict__ att,
                          float* __restrict__ ssrc, float* __restrict__ sdst) {
  __shared__ float As[128 * 64];
  __shared__ float Bs[64 * 64];
  int tid = threadIdx.x;
  int m0 = mi * 128, n0 = ni * 64;
  int tx = tid & 15, ty = tid >> 4;
  const float4* A4 = (const float4*)A;
  const float4* W4 = (const float4*)Wt;
  float acc[8][4] = {};

  for (int c = 0; c < K / 64; ++c) {
    __syncthreads();
    {
      int q = tid & 15;   // k-group slot within chunk
      int r0 = tid >> 4;  // 16 rows per pass
#pragma unroll
      for (int p = 0; p < 8; ++p) {  // A: 128 rows
        int r = r0 + p * 16;
        float4 v = A4[(size_t)(m0 + r) * (K / 4) + c * 16 + q];
        *(float4*)&As[r * 64 + ((q ^ ((r >> 2) & 15)) << 2)] = v;
      }
#pragma unroll
      for (int p = 0; p < 4; ++p) {  // B: 64 rows
        int r = r0 + p * 16;
        float4 v = W4[(size_t)(n0 + r) * (K / 4) + c * 16 + q];
        *(float4*)&Bs[r * 64 + ((q ^ ((r >> 2) & 15)) << 2)] = v;
      }
    }
    __syncthreads();
#pragma unroll 4
    for (int q = 0; q < 16; ++q) {
      float4 a[8], b[4];
#pragma unroll
      for (int i = 0; i < 8; ++i) {
        int r = ty * 8 + i;
        a[i] = *(const float4*)&As[r * 64 + ((q ^ ((r >> 2) & 15)) << 2)];
      }
#pragma unroll
      for (int j = 0; j < 4; ++j) {
        int rn = tx * 4 + j;
        b[j] = *(const float4*)&Bs[rn * 64 + ((q ^ ((rn >> 2) & 15)) << 2)];
      }
#pragma unroll
      for (int i = 0; i < 8; ++i)
#pragma unroll
        for (int j = 0; j < 4; ++j)
          acc[i][j] += a[i].x * b[j].x + a[i].y * b[j].y
                     + a[i].z * b[j].z + a[i].w * b[j].w;
    }
  }

  float bd[4] = {0.f, 0.f, 0.f, 0.f};
  int nc = n0 + tx * 4;
  if (b1) { bd[0] = b1[nc]; bd[1] = b1[nc+1]; bd[2] = b1[nc+2]; bd[3] = b1[nc+3]; }
  if (b2) { bd[0] += b2[nc]; bd[1] += b2[nc+1]; bd[2] += b2[nc+2]; bd[3] += b2[nc+3]; }
#pragma unroll
  for (int i = 0; i < 8; ++i) {
    int m = m0 + ty * 8 + i;
    int om = m;
    if (REMAP) {
      int node = m >> 2, v = m & 3;
      int b = node / NN, n = node - b * NN;
      om = (b * 4 + v) * NN + n;
    }
    float4 o = make_float4(acc[i][0] + bd[0], acc[i][1] + bd[1],
                           acc[i][2] + bd[2], acc[i][3] + bd[3]);
    *(float4*)&C[(size_t)om * N + nc] = o;
  }

  if (SCORE && m0 < NN) {  // uniform per block
    int hsel = tx >> 3;
    int h = ni * 2 + hsel;
    int kb = (tx & 7) * 4;
    float a0[4], a1[4];
#pragma unroll
    for (int j = 0; j < 4; ++j) {
      a0[j] = att[h * 64 + kb + j];
      a1[j] = att[h * 64 + 32 + kb + j];
    }
#pragma unroll
    for (int i = 0; i < 8; ++i) {
      int m = m0 + ty * 8 + i;
      float p0 = 0.f, p1 = 0.f;
#pragma unroll
      for (int j = 0; j < 4; ++j) {
        float g = acc[i][j];
        float lr = g > 0.f ? g : 0.2f * g;
        p0 += a0[j] * lr;
        p1 += a1[j] * lr;
      }
      p0 += __shfl_xor(p0, 1, 16); p1 += __shfl_xor(p1, 1, 16);
      p0 += __shfl_xor(p0, 2, 16); p1 += __shfl_xor(p1, 2, 16);
      p0 += __shfl_xor(p0, 4, 16); p1 += __shfl_xor(p1, 4, 16);
      if ((tx & 7) == 0 && m < NN) {
        ssrc[m * HEADS_ + h] = p0;
        sdst[m * HEADS_ + h] = p1;
      }
    }
  }
}

// -------- K1: blocks 0..249 = h-GEMM (125 m-tiles x 2 n-tiles) + score
//              blocks 250..249+EB = bucket build
__global__ __launch_bounds__(256) void k1_kernel(const float* __restrict__ x,
                                                 const float* __restrict__ W,
                                                 const float* __restrict__ att,
                                                 float* __restrict__ hbuf,
                                                 float* __restrict__ ssrc,
                                                 float* __restrict__ sdst,
                                                 const int* __restrict__ ei,
                                                 int* __restrict__ cnt,
                                                 int* __restrict__ elist) {
  int bid = blockIdx.x;
  if (bid < 250) {
    gemm_tile<64, 1, 0>(bid >> 1, bid & 1, x, W, nullptr, nullptr, hbuf, 128,
                        att, ssrc, sdst);
  } else {
    for (int e = (bid - 250) * 256 + threadIdx.x; e < ETOT; e += EB * 256) {
      int s, d;
      if (e < EE) { s = ei[e]; d = ei[EE + e]; }
      else { s = d = e - EE; }  // self loops
      int pos = atomicAdd(&cnt[d], 1);
      if (pos < CAP) elist[d * CAP + pos] = s;
    }
  }
}

// -------- K2: gather with in-block softmax (local denom), 2 dst/block
__global__ __launch_bounds__(256) void gather_kernel(const int* __restrict__ cnt,
                                                     const int* __restrict__ elist,
                                                     const float* __restrict__ ssrc,
                                                     const float* __restrict__ sdst,
                                                     const float* __restrict__ hbuf,
                                                     float* __restrict__ hgat) {
  __shared__ int   srcs[2][CAP];
  __shared__ float exs[2][CAP][HEADS_];
  int li = threadIdx.x >> 7;
  int t = threadIdx.x & 127;
  int d = blockIdx.x * 2 + li;  // global dst node id
  int b = d / NN;
  int v = t >> 5, q = t & 31, h = q >> 3;
  int m = cnt[d]; if (m > CAP) m = CAP;
  // stage src ids + exp(score per head): 4 threads per edge
  for (int base = 0; base < m; base += 32) {
    int i = base + (t >> 2);
    if (i < m) {
      int s = elist[d * CAP + i];
      if ((t & 3) == 0) srcs[li][i] = s;
      float sc = ssrc[s * HEADS_ + (t & 3)] + sdst[d * HEADS_ + (t & 3)];
      exs[li][i][t & 3] = __expf(sc);  // shift-invariant, scores O(1)
    }
  }
  __syncthreads();
  // denom over ALL edges; numerator over same-block srcs (h_full block-diag)
  float den = 1e-16f;
  float4 acc = make_float4(0.f, 0.f, 0.f, 0.f);
  const float* hbase = hbuf + ((size_t)(b * 4 + v) * NN) * DM + q * 4;
  for (int i = 0; i < m; ++i) {
    float ex = exs[li][i][h];
    den += ex;
    unsigned sl = (unsigned)(srcs[li][i] - b * NN);
    if (sl < NN) {
      float4 hv = *(const float4*)(hbase + (size_t)sl * DM);
      acc.x += ex * hv.x; acc.y += ex * hv.y;
      acc.z += ex * hv.z; acc.w += ex * hv.w;
    }
  }
  float r = 1.f / den;
  acc.x *= r; acc.y *= r; acc.z *= r; acc.w *= r;
  *(float4*)&hgat[((size_t)(d * 4 + v)) * DM + q * 4] = acc;  // node-major
}

// -------- K3: qkv GEMM wrapper (node-major, M=16000, K=128, N=384)
__global__ __launch_bounds__(256) void qkv_kernel(const float* __restrict__ hgat,
                                                  const float* __restrict__ inw,
                                                  const float* __restrict__ inb,
                                                  float* __restrict__ qkv) {
  gemm_tile<128, 0, 0>(blockIdx.x, blockIdx.y, hgat, inw, inb, nullptr, qkv,
                       384, nullptr, nullptr, nullptr);
}

// -------- K4: attention over V, 2 nodes/block, node-major qkv/ao
__global__ __launch_bounds__(256) void attn_kernel(const float* __restrict__ qkv,
                                                   float* __restrict__ ao) {
  int li = threadIdx.x >> 7;
  int t = threadIdx.x & 127;
  int node = blockIdx.x * 2 + li;  // 0..3999
  __shared__ float qs[2][4][DM], ks[2][4][DM], vs[2][4][DM];
  __shared__ float aw[2][4][HEADS_][4];
#pragma unroll
  for (int v = 0; v < 4; ++v) {
    size_t base = (size_t)(node * 4 + v) * 384;  // contiguous rows
    qs[li][v][t] = qkv[base + t];
    ks[li][v][t] = qkv[base + 128 + t];
    vs[li][v][t] = qkv[base + 256 + t];
  }
  __syncthreads();
  if (t < 64) {  // (vq, vk, h) dot products, length 32
    int vq = t >> 4, vk = (t >> 2) & 3, h = t & 3;
    float acc = 0.f;
#pragma unroll
    for (int kd = 0; kd < 32; ++kd)
      acc += qs[li][vq][h * 32 + kd] * ks[li][vk][h * 32 + kd];
    aw[li][vq][h][vk] = acc * 0.17677669529663687f;  // 1/sqrt(32)
  }
  __syncthreads();
  if (t < 16) {  // softmax over vk per (vq, h)
    int vq = t >> 2, h = t & 3;
    float mx = aw[li][vq][h][0];
    for (int i = 1; i < 4; ++i) mx = fmaxf(mx, aw[li][vq][h][i]);
    float e[4], s = 0.f;
    for (int i = 0; i < 4; ++i) { e[i] = __expf(aw[li][vq][h][i] - mx); s += e[i]; }
    for (int i = 0; i < 4; ++i) aw[li][vq][h][i] = e[i] / s;
  }
  __syncthreads();
  int h = t >> 5;
#pragma unroll
  for (int vq = 0; vq < 4; ++vq) {
    float acc = 0.f;
#pragma unroll
    for (int vk = 0; vk < 4; ++vk) acc += aw[li][vq][h][vk] * vs[li][vk][t];
    ao[(size_t)(node * 4 + vq) * DM + t] = acc;
  }
}

// -------- K5: out_proj GEMM wrapper, remap rows to (b,v,n) output order
__global__ __launch_bounds__(256) void outproj_kernel(const float* __restrict__ ao,
                                                      const float* __restrict__ outw,
                                                      const float* __restrict__ outb,
                                                      const float* __restrict__ bias,
                                                      float* __restrict__ out) {
  gemm_tile<128, 0, 1>(blockIdx.x, blockIdx.y, ao, outw, outb, bias, out, 128,
                       nullptr, nullptr, nullptr);
}

extern "C" void kernel_launch(void* const* d_in, const int* in_sizes, int n_in,
                              void* d_out, int out_size, void* d_ws, size_t ws_size,
                              hipStream_t stream) {
  const float* x    = (const float*)d_in[0];
  const float* W    = (const float*)d_in[1];
  const float* att  = (const float*)d_in[2];
  const float* inw  = (const float*)d_in[3];
  const float* inb  = (const float*)d_in[4];
  const float* outw = (const float*)d_in[5];
  const float* outb = (const float*)d_in[6];
  const float* bias = (const float*)d_in[7];
  const int*   ei   = (const int*)d_in[8];
  float* out = (float*)d_out;

  float* ws = (float*)d_ws;
  float* hbuf  = ws;                       // 2,048,000  (b,v,n)-major h
  float* hgat  = ws + 2100000;             // 2,048,000  node-major
  float* qkv   = ws + 4200000;             // 6,144,000  node-major
  float* ao    = ws + 10400000;            // 2,048,000  node-major
  float* ssrc  = ws + 12500000;            // 16,000 } contiguous:
  float* sdst  = ssrc + 16000;             // 16,000 } one 144 KB memset
  int*   cnt   = (int*)(sdst + 16000);     //  4,000 }
  int*   elist = cnt + 4000;               // 192,000 (4000 x CAP)

  // zero ssrc/sdst (rows >=1000 must stay zero) + cnt
  hipMemsetAsync(ssrc, 0, 36000 * sizeof(float), stream);

  k1_kernel<<<250 + EB, 256, 0, stream>>>(x, W, att, hbuf, ssrc, sdst, ei, cnt, elist);
  gather_kernel<<<NTOT / 2, 256, 0, stream>>>(cnt, elist, ssrc, sdst, hbuf, hgat);
  qkv_kernel<<<dim3(125, 6), 256, 0, stream>>>(hgat, inw, inb, qkv);
  attn_kernel<<<NTOT / 2, 256, 0, stream>>>(qkv, ao);
  outproj_kernel<<<dim3(125, 2), 256, 0, stream>>>(ao, outw, outb, bias, out);
}